// Round 7
// baseline (220.445 us; speedup 1.0000x reference)
//
#include <hip/hip_runtime.h>
#include <hip/hip_bf16.h>

#define NUM_GENES 4384
#define GPAD 4608        // 18 * 256 (pad resident dim; 256 rows per block)
#define DM 128
#define ROWB 256         // bytes per bf16 row (128*2)
#define LDS_STRIDE 272   // 256 + 16B pad (b128 4-way = data floor, not a real conflict)
#define NTILES 137       // 4384 / 32
#define RB_BLOCKS 18
#define NCHUNK 6
#define TPC 23           // 5 chunks of 23 + 1 of 22

typedef __attribute__((ext_vector_type(8))) short short8;
typedef __attribute__((ext_vector_type(16))) float floatx16;

#if defined(__has_builtin)
#  if __has_builtin(__builtin_amdgcn_exp2f)
#    define FAST_EXP2(x) __builtin_amdgcn_exp2f(x)
#  endif
#endif
#ifndef FAST_EXP2
#  define FAST_EXP2(x) exp2f(x)
#endif

static __device__ __forceinline__ short bf16bits(float x) {
    __hip_bfloat16 h = __float2bfloat16(x);
    return *(short*)&h;
}

// Fused prep, 8 outputs/thread, 16B stores.
// Q: blocks [0,2304)  K: [2304,2592)  zero l/mean: [2592,2610)
__global__ __launch_bounds__(256)
void prep_all(const float* __restrict__ mut, const float* __restrict__ W_in,
              const float* __restrict__ b_in, const float* __restrict__ key,
              __hip_bfloat16* __restrict__ Qb, __hip_bfloat16* __restrict__ Kb,
              float* __restrict__ l, float* __restrict__ meanbuf) {
    int bx = blockIdx.x, t = threadIdx.x;
    if (bx < 2304) {                        // Q: 8*4608*128 elems, 8 per thread
        int i = bx * 256 + t;               // [0, 589824)
        int d0 = (i & 15) * 8;
        int g = (i >> 4) % GPAD;
        int b = i / (GPAD * 16);
        short8 o;
        if (g < NUM_GENES) {
            const float4 mv = *(const float4*)(mut + ((size_t)b * NUM_GENES + g) * 4);
            const float sc = 0.08838834764831845f * 1.4426950408889634f; // 1/sqrt(128)*log2(e)
#pragma unroll
            for (int j = 0; j < 8; ++j) {
                int d = d0 + j;
                float v = b_in[d] + mv.x * W_in[d] + mv.y * W_in[128 + d]
                                  + mv.z * W_in[256 + d] + mv.w * W_in[384 + d];
                o[j] = bf16bits(v * sc);
            }
        } else {
#pragma unroll
            for (int j = 0; j < 8; ++j) o[j] = 0;
        }
        *(short8*)((short*)Qb + (size_t)i * 8) = o;
    } else if (bx < 2592) {                 // K: 4608*128 elems, 8 per thread
        int i = (bx - 2304) * 256 + t;      // [0, 73728)
        int g = i >> 4;
        short8 o;
        if (g < NUM_GENES) {
            const float4 k0 = *(const float4*)(key + (size_t)i * 8);
            const float4 k1 = *(const float4*)(key + (size_t)i * 8 + 4);
            o[0] = bf16bits(k0.x); o[1] = bf16bits(k0.y);
            o[2] = bf16bits(k0.z); o[3] = bf16bits(k0.w);
            o[4] = bf16bits(k1.x); o[5] = bf16bits(k1.y);
            o[6] = bf16bits(k1.z); o[7] = bf16bits(k1.w);
        } else {
#pragma unroll
            for (int j = 0; j < 8; ++j) o[j] = 0;
        }
        *(short8*)((short*)Kb + (size_t)i * 8) = o;
    } else {                                // zero: 18 blocks cover lbuf (36864 floats)
        int i = (bx - 2592) * 256 + t;      // [0, 4608)
        float4 z = {0.f, 0.f, 0.f, 0.f};
        *(float4*)(l + (size_t)i * 8) = z;
        *(float4*)(l + (size_t)i * 8 + 4) = z;
        if (bx == 2592 && t < 128) {        // meanbuf: 1024 floats
            *(float4*)(meanbuf + t * 8) = z;
            *(float4*)(meanbuf + t * 8 + 4) = z;
        }
    }
}

// Unified phase kernel, 64 resident rows/wave, double-buffered LDS (1 barrier/tile),
// persistent-zero C operand (no per-tile acc re-init).
// PB=false: resident=Q (per b), stream=K, epilogue: atomicAdd rowsums -> lbuf.
// PB=true : resident=K, stream=Q (per b), scale exp2 by 1/l[q]; epilogue: block's
//           256 partial w values -> LDS -> partial (w @ V) -> atomicAdd meanbuf.
// A/B frag: lane holds row/col (lane&31), 16B at byte dsl*32 + (lane>>5)*16.
// C/D: col=lane&31, row=(r&3)+8*(r>>2)+4*(lane>>5).
template <bool PB>
__global__ __launch_bounds__(256)
void phase_kernel(const __hip_bfloat16* __restrict__ Qb,
                  const __hip_bfloat16* __restrict__ Kb,
                  const float* __restrict__ lsum,
                  const float* __restrict__ V,
                  float* __restrict__ out) {
    __shared__ __align__(16) char tile[2][32 * LDS_STRIDE];
    __shared__ float sw[256];   // PB only: block's partial w values

    int rb    = blockIdx.x;   // resident 256-row block, 0..17
    int chunk = blockIdx.y;   // 0..5 over stream tiles
    int b     = blockIdx.z;   // batch

    const char* resident = (const char*)(PB ? Kb : (Qb + (size_t)b * GPAD * DM));
    const char* stream   = (const char*)(PB ? (Qb + (size_t)b * GPAD * DM) : Kb);

    int t = threadIdx.x;
    int lane = t & 63, wid = t >> 6;
    int m = lane & 31, half = lane >> 5;

    // Resident A fragments: 64 rows per wave (two 32-row groups), in VGPRs.
    short8 afrag[2][8];
#pragma unroll
    for (int g = 0; g < 2; ++g) {
        const char* arow = resident + (size_t)(rb * 256 + wid * 64 + g * 32 + m) * ROWB;
#pragma unroll
        for (int dsl = 0; dsl < 8; ++dsl)
            afrag[g][dsl] = *(const short8*)(arow + dsl * 32 + half * 16);
    }

    floatx16 z;   // persistent zero C operand: kills per-tile acc zero-init VALU
#pragma unroll
    for (int r = 0; r < 16; ++r) z[r] = 0.f;

    float lacc[2][16];
#pragma unroll
    for (int g = 0; g < 2; ++g)
#pragma unroll
        for (int r = 0; r < 16; ++r) lacc[g][r] = 0.f;

    int t0 = chunk * TPC;
    int t1 = min(NTILES, t0 + TPC);
    int sr = t >> 3, sc = t & 7;   // staging: thread -> (row, 32B chunk)
    int soff = sr * LDS_STRIDE + sc * 32;

    // Pre-loop: load tile t0 into buf 0.
    {
        const char* src = stream + (size_t)(t0 * 32 + sr) * ROWB + sc * 32;
        float4 v0 = *(const float4*)src;
        float4 v1 = *(const float4*)(src + 16);
        *(float4*)(tile[0] + soff) = v0;
        *(float4*)(tile[0] + soff + 16) = v1;
    }

    int p = 0;
    for (int kt = t0; kt < t1; ++kt) {
        bool more = (kt + 1 < t1);
        float4 v0, v1;
        if (more) {   // next tile's global loads; latency hidden by MFMA below
            const char* s2 = stream + (size_t)((kt + 1) * 32 + sr) * ROWB + sc * 32;
            v0 = *(const float4*)s2;
            v1 = *(const float4*)(s2 + 16);
        }
        __syncthreads();   // buf[p] fully written; prior reads of buf[p^1] done

        const char* tp = tile[p];
        short8 bfrag = *(const short8*)(tp + m * LDS_STRIDE + half * 16);
        floatx16 acc0 = __builtin_amdgcn_mfma_f32_32x32x16_bf16(afrag[0][0], bfrag, z, 0, 0, 0);
        floatx16 acc1 = __builtin_amdgcn_mfma_f32_32x32x16_bf16(afrag[1][0], bfrag, z, 0, 0, 0);
#pragma unroll
        for (int dsl = 1; dsl < 8; ++dsl) {
            bfrag = *(const short8*)(tp + m * LDS_STRIDE + dsl * 32 + half * 16);
            acc0 = __builtin_amdgcn_mfma_f32_32x32x16_bf16(afrag[0][dsl], bfrag, acc0, 0, 0, 0);
            acc1 = __builtin_amdgcn_mfma_f32_32x32x16_bf16(afrag[1][dsl], bfrag, acc1, 0, 0, 0);
        }

        if (more) {   // stage next tile into the other buffer
            char* tn = tile[p ^ 1];
            *(float4*)(tn + soff) = v0;
            *(float4*)(tn + soff + 16) = v1;
        }

        if (PB) {
            float scl = __builtin_amdgcn_rcpf(lsum[b * GPAD + kt * 32 + m]);
#pragma unroll
            for (int r = 0; r < 16; ++r) {
                lacc[0][r] = fmaf(FAST_EXP2(acc0[r]), scl, lacc[0][r]);
                lacc[1][r] = fmaf(FAST_EXP2(acc1[r]), scl, lacc[1][r]);
            }
        } else {
#pragma unroll
            for (int r = 0; r < 16; ++r) {
                lacc[0][r] += FAST_EXP2(acc0[r]);
                lacc[1][r] += FAST_EXP2(acc1[r]);
            }
        }
        p ^= 1;
    }

    // Reduce across the 32 columns (lanes sharing the same 'half').
#pragma unroll
    for (int off = 1; off <= 16; off <<= 1)
#pragma unroll
        for (int g = 0; g < 2; ++g)
#pragma unroll
            for (int r = 0; r < 16; ++r)
                lacc[g][r] += __shfl_xor(lacc[g][r], off, 64);

    if (!PB) {
        if (m == 0) {   // lanes 0 and 32 hold sums for rows (+0 / +4)
#pragma unroll
            for (int g = 0; g < 2; ++g) {
                float* ob = out + b * GPAD + rb * 256 + wid * 64 + g * 32 + 4 * half;
#pragma unroll
                for (int r = 0; r < 16; ++r)
                    atomicAdd(ob + (r & 3) + 8 * (r >> 2), lacc[g][r]);
            }
        }
    } else {
        // Stash this block's 256 partial w values in LDS (pad rows -> 0).
        __syncthreads();   // all waves done with tile/MFMA reads
        if (m == 0) {
#pragma unroll
            for (int g = 0; g < 2; ++g) {
                int base = wid * 64 + g * 32 + 4 * half;
#pragma unroll
                for (int r = 0; r < 16; ++r) {
                    int rl = base + (r & 3) + 8 * (r >> 2);
                    sw[rl] = (rb * 256 + rl < NUM_GENES) ? lacc[g][r] : 0.f;
                }
            }
        }
        __syncthreads();
        // Partial mean: meanbuf[b,d] += sum_{k in block rows} sw[k] * V[k,d]
        int d = t & 127, hf = t >> 7;      // hf selects 128-row half
        int gbase = rb * 256 + hf * 128;
        int cnt = NUM_GENES - gbase;
        if (cnt > 128) cnt = 128;
        if (cnt > 0) {
            const float* swp = sw + hf * 128;
            const float* Vp = V + (size_t)gbase * 128 + d;
            float a0 = 0.f, a1 = 0.f;
            int k = 0;
            for (; k + 1 < cnt; k += 2) {
                a0 += swp[k] * Vp[(size_t)k * 128];
                a1 += swp[k + 1] * Vp[(size_t)(k + 1) * 128];
            }
            if (k < cnt) a0 += swp[k] * Vp[(size_t)k * 128];
            atomicAdd(out + b * 128 + d, a0 + a1);   // out == meanbuf in PB
        }
    }
}

// h = gelu(mean/G @ W1 + b1) ; out = h@W2 + b2.  grid 8, block 64.
__global__ void mlp_k(const float* __restrict__ meanbuf,
                      const float* __restrict__ W1, const float* __restrict__ b1,
                      const float* __restrict__ W2, const float* __restrict__ b2,
                      float* __restrict__ out) {
    int b = blockIdx.x, t = threadIdx.x;
    __shared__ float sh[64];
    const float* mb = meanbuf + b * 128;
    float s = b1[t];
    for (int d = 0; d < 128; ++d)
        s += (mb[d] * (1.0f / 4384.0f)) * W1[d * 64 + t];
    sh[t] = 0.5f * s * (1.0f + erff(s * 0.70710678118654752f));   // exact gelu
    __syncthreads();
    if (t < 26) {
        float o = b2[t];
        for (int j = 0; j < 64; ++j) o += sh[j] * W2[j * 26 + t];
        out[b * 26 + t] = o;
    }
}

extern "C" void kernel_launch(void* const* d_in, const int* in_sizes, int n_in,
                              void* d_out, int out_size, void* d_ws, size_t ws_size,
                              hipStream_t stream) {
    const float* mut  = (const float*)d_in[0];   // [8,4384,4]
    const float* V    = (const float*)d_in[1];   // [4384,128]
    const float* W_in = (const float*)d_in[2];   // [4,128]
    const float* b_in = (const float*)d_in[3];   // [128]
    const float* key  = (const float*)d_in[4];   // [4384,128]
    const float* W1   = (const float*)d_in[5];   // [128,64]
    const float* b1   = (const float*)d_in[6];   // [64]
    const float* W2   = (const float*)d_in[7];   // [64,26]
    const float* b2   = (const float*)d_in[8];   // [26]
    float* out = (float*)d_out;                  // [8,26]

    char* ws = (char*)d_ws;
    __hip_bfloat16* Qb = (__hip_bfloat16*)(ws);                    // 9,437,184
    __hip_bfloat16* Kb = (__hip_bfloat16*)(ws + 9437184);          // 1,179,648
    float* lbuf        = (float*)(ws + 10616832);                  //   147,456
    float* meanbuf     = (float*)(ws + 10764288);                  //     4,096

    prep_all<<<2610, 256, 0, stream>>>(mut, W_in, b_in, key, Qb, Kb, lbuf, meanbuf);

    dim3 grid(RB_BLOCKS, NCHUNK, 8);
    // Phase A: l = rowsum exp2(QK^T)
    phase_kernel<false><<<grid, 256, 0, stream>>>(Qb, Kb, lbuf, V, lbuf);
    // Phase B + mean fused: meanbuf[b,d] += (partial colsum softmax) @ V
    phase_kernel<true><<<grid, 256, 0, stream>>>(Qb, Kb, lbuf, V, meanbuf);

    mlp_k<<<8, 64, 0, stream>>>(meanbuf, W1, b1, W2, b2, out);
}